// Round 4
// baseline (944.622 us; speedup 1.0000x reference)
//
#include <hip/hip_runtime.h>
#include <math.h>

#define NF 128      // feature/hidden dim (F == H == 128)
#define TROWS 32    // fused-kernel tile rows (16 KB LDS -> 8 blocks/CU)

// ---------- setup kernels ----------

__global__ void k_deg(const int* __restrict__ ei, int* cnt, int E) {
    int e = blockIdx.x * blockDim.x + threadIdx.x;
    if (e < E) atomicAdd(&cnt[ei[E + e]], 1);   // dst row; cnt = deg w/o self-loop
}

// Block-level exclusive scan over (cnt+1), also emits dinv = rsqrt(deg+1).
__global__ void k_scan1(const int* __restrict__ cnt, float* dinv,
                        int* offs, int* bsum, int n) {
    __shared__ int s[256];
    int t = threadIdx.x;
    int i = blockIdx.x * 256 + t;
    int v = 0;
    if (i < n) {
        v = cnt[i] + 1;                 // +1 self-loop
        dinv[i] = 1.0f / sqrtf((float)v);
    }
    s[t] = v;
    for (int d = 1; d < 256; d <<= 1) {
        __syncthreads();
        int add = (t >= d) ? s[t - d] : 0;
        __syncthreads();
        s[t] += add;
    }
    __syncthreads();
    if (i < n) offs[i] = s[t] - v;          // exclusive
    if (t == 255) bsum[blockIdx.x] = s[255]; // block total
}

// Single-block exclusive scan of block sums (nb <= 512).
__global__ void k_scan2(int* bsum, int nb) {
    __shared__ int s[512];
    int t = threadIdx.x;
    int v = (t < nb) ? bsum[t] : 0;
    s[t] = v;
    for (int d = 1; d < 512; d <<= 1) {
        __syncthreads();
        int add = (t >= d) ? s[t - d] : 0;
        __syncthreads();
        s[t] += add;
    }
    __syncthreads();
    if (t < nb) bsum[t] = s[t] - v;         // exclusive
}

__global__ void k_scan3(int* offs, const int* __restrict__ bsum, int* cursor, int n, int total) {
    int i = blockIdx.x * 256 + threadIdx.x;
    if (i < n) {
        int o = offs[i] + bsum[blockIdx.x];
        offs[i] = o;
        cursor[i] = o;
    }
    if (i == 0) offs[n] = total;
}

// Scatter edges (+ self loops) into dst-sorted CSR; pack (src, norm) in int2.
__global__ void k_fill(const int* __restrict__ ei, const float* __restrict__ dinv,
                       int* cursor, int2* pk, int E, int n) {
    int t = blockIdx.x * blockDim.x + threadIdx.x;
    if (t < E) {
        int s = ei[t], d = ei[E + t];
        int p = atomicAdd(&cursor[d], 1);
        pk[p] = make_int2(s, __float_as_int(dinv[s] * dinv[d]));
    } else if (t < E + n) {
        int i = t - E;
        int p = atomicAdd(&cursor[i], 1);
        float di = dinv[i];
        pk[p] = make_int2(i, __float_as_int(di * di));
    }
}

// ---------- fused layer: gather-aggregate into LDS tile, then GEMM+bias+ReLU ----------
// Grid-stride persistent over 32-row tiles. 16 KB LDS -> 8 blocks/CU (thread cap).
// Gather: 8 groups x 4 rows, float4/lane (full 512B row per 32-lane group),
// edges unrolled x4. GEMM: As reads broadcast within group (conflict-free).
__global__ __launch_bounds__(256, 8) void k_fused(
        const float* __restrict__ hin, const int* __restrict__ offs,
        const int2* __restrict__ pk, const float* __restrict__ W,
        const float* __restrict__ bias, float* __restrict__ out,
        int n, int ntiles) {
    __shared__ float As[TROWS * NF];
    int tid = threadIdx.x;
    int grp = tid >> 5;          // 0..7
    int c4 = (tid & 31) << 2;    // float4 column offset

    for (int tile = blockIdx.x; tile < ntiles; tile += gridDim.x) {
        int row0 = tile * TROWS;

        // ---- gather/aggregate phase ----
        #pragma unroll
        for (int i = 0; i < 4; ++i) {
            int r = grp * 4 + i;
            int node = row0 + r;
            float4 acc = make_float4(0.f, 0.f, 0.f, 0.f);
            if (node < n) {
                int b = offs[node], e = offs[node + 1];
                int j = b;
                for (; j + 4 <= e; j += 4) {
                    int2 p0 = pk[j], p1 = pk[j + 1], p2 = pk[j + 2], p3 = pk[j + 3];
                    float4 r0 = *(const float4*)(hin + (size_t)p0.x * NF + c4);
                    float4 r1 = *(const float4*)(hin + (size_t)p1.x * NF + c4);
                    float4 r2 = *(const float4*)(hin + (size_t)p2.x * NF + c4);
                    float4 r3 = *(const float4*)(hin + (size_t)p3.x * NF + c4);
                    float w0 = __int_as_float(p0.y), w1 = __int_as_float(p1.y);
                    float w2 = __int_as_float(p2.y), w3 = __int_as_float(p3.y);
                    acc.x += w0*r0.x + w1*r1.x + w2*r2.x + w3*r3.x;
                    acc.y += w0*r0.y + w1*r1.y + w2*r2.y + w3*r3.y;
                    acc.z += w0*r0.z + w1*r1.z + w2*r2.z + w3*r3.z;
                    acc.w += w0*r0.w + w1*r1.w + w2*r2.w + w3*r3.w;
                }
                for (; j < e; ++j) {
                    int2 p = pk[j];
                    float4 rr = *(const float4*)(hin + (size_t)p.x * NF + c4);
                    float w = __int_as_float(p.y);
                    acc.x += w * rr.x; acc.y += w * rr.y;
                    acc.z += w * rr.z; acc.w += w * rr.w;
                }
            }
            *(float4*)(As + r * NF + c4) = acc;
        }
        __syncthreads();

        // ---- GEMM + bias + ReLU phase: rows grp*4..grp*4+3, cols c4..c4+3 ----
        float4 acc[4];
        #pragma unroll
        for (int j = 0; j < 4; ++j) acc[j] = make_float4(0.f, 0.f, 0.f, 0.f);

        const float* Wp = W + c4;
        const float* Ap = As + grp * 4 * NF;
        for (int k = 0; k < 128; k += 4) {
            float4 w0 = *(const float4*)(Wp + (k + 0) * NF);
            float4 w1 = *(const float4*)(Wp + (k + 1) * NF);
            float4 w2 = *(const float4*)(Wp + (k + 2) * NF);
            float4 w3 = *(const float4*)(Wp + (k + 3) * NF);
            #pragma unroll
            for (int j = 0; j < 4; ++j) {
                float4 a = *(const float4*)(Ap + j * NF + k);
                acc[j].x += a.x * w0.x + a.y * w1.x + a.z * w2.x + a.w * w3.x;
                acc[j].y += a.x * w0.y + a.y * w1.y + a.z * w2.y + a.w * w3.y;
                acc[j].z += a.x * w0.z + a.y * w1.z + a.z * w2.z + a.w * w3.z;
                acc[j].w += a.x * w0.w + a.y * w1.w + a.z * w2.w + a.w * w3.w;
            }
        }

        float4 bv = *(const float4*)(bias + c4);
        #pragma unroll
        for (int j = 0; j < 4; ++j) {
            int gr = row0 + grp * 4 + j;
            if (gr < n) {
                float4 o;
                o.x = fmaxf(acc[j].x + bv.x, 0.f);
                o.y = fmaxf(acc[j].y + bv.y, 0.f);
                o.z = fmaxf(acc[j].z + bv.z, 0.f);
                o.w = fmaxf(acc[j].w + bv.w, 0.f);
                *(float4*)(out + (size_t)gr * NF + c4) = o;
            }
        }
        __syncthreads();   // As reused next tile
    }
}

// ---------- fused pool + head (batch sorted -> contiguous ranges; bounds inline) ----------

__global__ __launch_bounds__(256) void k_poolfinal(const float* __restrict__ h,
        const int* __restrict__ batch, const float* __restrict__ linW,
        const float* __restrict__ linb, float* __restrict__ outp, int N) {
    int g = blockIdx.x;
    int tid = threadIdx.x;
    __shared__ int sb[2];
    if (tid < 2) {                       // lower_bound(batch, g+tid)
        int target = g + tid;
        int lo = 0, hi = N;
        while (lo < hi) {
            int mid = (lo + hi) >> 1;
            if (batch[mid] < target) lo = mid + 1; else hi = mid;
        }
        sb[tid] = lo;
    }
    __syncthreads();
    int b = sb[0], e = sb[1];

    int grp = tid >> 5, c4 = (tid & 31) << 2;
    float4 acc = make_float4(0.f, 0.f, 0.f, 0.f);
    for (int i = b + grp; i < e; i += 8) {
        float4 v = *(const float4*)(h + (size_t)i * NF + c4);
        acc.x += v.x; acc.y += v.y; acc.z += v.z; acc.w += v.w;
    }
    __shared__ float red[8][NF];
    *(float4*)(&red[grp][c4]) = acc;
    __syncthreads();

    float v0 = 0.f, v1 = 0.f;
    if (tid < NF) {
        float s = 0.f;
        #pragma unroll
        for (int gg = 0; gg < 8; ++gg) s += red[gg][tid];
        v0 = s * linW[tid * 2 + 0];
        v1 = s * linW[tid * 2 + 1];
    }
    #pragma unroll
    for (int d = 32; d > 0; d >>= 1) {
        v0 += __shfl_down(v0, d);
        v1 += __shfl_down(v1, d);
    }
    __shared__ float sv[8];
    if ((tid & 63) == 0) { sv[(tid >> 6) * 2] = v0; sv[(tid >> 6) * 2 + 1] = v1; }
    __syncthreads();
    if (tid == 0) {
        float inv = 1.0f / fmaxf((float)(e - b), 1.0f);
        outp[g * 2 + 0] = (sv[0] + sv[2]) * inv + linb[0];
        outp[g * 2 + 1] = (sv[1] + sv[3]) * inv + linb[1];
    }
}

// ---------- launcher ----------

extern "C" void kernel_launch(void* const* d_in, const int* in_sizes, int n_in,
                              void* d_out, int out_size, void* d_ws, size_t ws_size,
                              hipStream_t stream) {
    const float* x     = (const float*)d_in[0];
    const int*   ei    = (const int*)d_in[1];
    const int*   batch = (const int*)d_in[2];
    const float* Wl[4] = {(const float*)d_in[3], (const float*)d_in[5],
                          (const float*)d_in[7], (const float*)d_in[9]};
    const float* bl[4] = {(const float*)d_in[4], (const float*)d_in[6],
                          (const float*)d_in[8], (const float*)d_in[10]};
    const float* linW  = (const float*)d_in[11];
    const float* linb  = (const float*)d_in[12];
    float* out = (float*)d_out;

    const int N  = in_sizes[2];
    const int E  = in_sizes[1] / 2;
    const int G  = out_size / 2;
    const int Et = E + N;

    // carve workspace (256B-aligned slices)
    char* p = (char*)d_ws;
    auto carve = [&](size_t bytes) -> char* {
        char* r = p;
        p += (bytes + 255) & ~(size_t)255;
        return r;
    };
    int*   cnt    = (int*)  carve((size_t)N * 4);
    float* dinv   = (float*)carve((size_t)N * 4);
    int*   offs   = (int*)  carve((size_t)(N + 1) * 4);
    int*   cursor = (int*)  carve((size_t)N * 4);
    int*   bsum   = (int*)  carve(512 * 4);
    int2*  pk     = (int2*) carve((size_t)Et * 8);
    float* bufA   = (float*)carve((size_t)N * NF * 4);   // h ping
    float* bufB   = (float*)carve((size_t)N * NF * 4);   // h pong

    hipMemsetAsync(cnt, 0, (size_t)N * 4, stream);
    k_deg<<<(E + 255) / 256, 256, 0, stream>>>(ei, cnt, E);

    int nb = (N + 255) / 256;   // 391 <= 512
    k_scan1<<<nb, 256, 0, stream>>>(cnt, dinv, offs, bsum, N);
    k_scan2<<<1, 512, 0, stream>>>(bsum, nb);
    k_scan3<<<nb, 256, 0, stream>>>(offs, bsum, cursor, N, Et);
    k_fill<<<(Et + 255) / 256, 256, 0, stream>>>(ei, dinv, cursor, pk, E, N);

    int ntiles = (N + TROWS - 1) / TROWS;
    int ngrid = ntiles < 2048 ? ntiles : 2048;   // 8 blocks/CU x 256 CUs
    const float* hin = x;
    float* hout = bufA;
    for (int l = 0; l < 4; ++l) {
        k_fused<<<ngrid, 256, 0, stream>>>(hin, offs, pk, Wl[l], bl[l], hout, N, ntiles);
        hin = hout;
        hout = (hout == bufA) ? bufB : bufA;
    }

    k_poolfinal<<<G, 256, 0, stream>>>((const float*)hin, batch, linW, linb, out, N);
}